// Round 14
// baseline (35.721 us; speedup 1.0000x reference)
//
#include <hip/hip_runtime.h>
#include <hip/hip_bf16.h>

#define BB    8
#define CC    128
#define TLEN  8192
#define TSPAN 128                    // t per block
#define KC    32                     // c per K-chunk
#define NB    (BB * (TLEN / TSPAN))  // 512 blocks = 2/CU

typedef __attribute__((ext_vector_type(8))) short short8;
typedef __attribute__((ext_vector_type(4))) float f32x4;

__device__ __forceinline__ short f2bf(float f) {
    union { float f; unsigned u; } v; v.f = f;
    return (short)((v.u + 0x7FFFu + ((v.u >> 16) & 1u)) >> 16);
}
__device__ __forceinline__ float bf2f(unsigned short h) {
    union { unsigned u; float f; } v; v.u = ((unsigned)h) << 16;
    return v.f;
}
// ybf col swizzle: spreads the 64B-row bank period across t (<=4-way residual)
__device__ __forceinline__ int ysw(int t, int c) {
    return c ^ (((t >> 3) & 3) << 3);
}

#define VMWAIT(N) asm volatile("s_waitcnt vmcnt(" #N ")" ::: "memory")
#define SB0 __builtin_amdgcn_sched_barrier(0)

__device__ __forceinline__ void bar_lgkm() {
    asm volatile("s_waitcnt lgkmcnt(0)" ::: "memory");
    __builtin_amdgcn_s_barrier();
}

typedef __attribute__((address_space(1))) const unsigned GU;
typedef __attribute__((address_space(3))) unsigned LU;
__device__ __forceinline__ void glds16(const float* g, const float* l) {
    __builtin_amdgcn_global_load_lds((GU*)g, (LU*)l, 16, 0, 0);
}

__global__ __launch_bounds__(512, 4)
void cfm_fused(const float* __restrict__ x1, const float* __restrict__ tsm,
               const float* __restrict__ z, const float* __restrict__ W,
               const float* __restrict__ blin, const int* __restrict__ xlens,
               const int* __restrict__ plens, float* __restrict__ out)
{
    __shared__ float xf[2][KC * TSPAN];   // f32 [32c][128t] linear, dbuf, 32 KB
    __shared__ float zf[2][KC * TSPAN];   // 32 KB
    __shared__ short ybf[TSPAN][KC];      // bf16 y [t][c-local], ysw cols, 8 KB
    __shared__ float red[8];

    const int bi = blockIdx.x;
    const int b  = bi & 7;
    const int t0 = (bi >> 3) * TSPAN;

    const int tid  = threadIdx.x;
    const int lane = tid & 63;
    const int wid  = tid >> 6;          // 0..7
    const int r15  = lane & 15;
    const int q4   = lane >> 4;

    const float ts  = tsm[b];
    const int   pl  = plens[b];
    const int   xl  = xlens[b];
    const float oms = 0.999999f;        // 1 - sigma
    const float cz  = 1.0f - oms * ts;
    const float cx  = ts;
    const size_t gB = (size_t)b * CC * TLEN;

    // ---- prologue: W A-frags (d row = wid*16+r15, k = ks*32+q4*8+e) + bias ----
    short8 af[4];
    {
        const int row = wid * 16 + r15;
        #pragma unroll
        for (int ks = 0; ks < 4; ++ks) {
            const float4 w0 = *reinterpret_cast<const float4*>(W + row * CC + ks * 32 + q4 * 8);
            const float4 w1 = *reinterpret_cast<const float4*>(W + row * CC + ks * 32 + q4 * 8 + 4);
            short8 a;
            a[0] = f2bf(w0.x); a[1] = f2bf(w0.y); a[2] = f2bf(w0.z); a[3] = f2bf(w0.w);
            a[4] = f2bf(w1.x); a[5] = f2bf(w1.y); a[6] = f2bf(w1.z); a[7] = f2bf(w1.w);
            af[ks] = a;
        }
    }
    float bl[4];
    #pragma unroll
    for (int rr = 0; rr < 4; ++rr) bl[rr] = blin[wid * 16 + q4 * 4 + rr];
    SB0;

    // ---- DMA: chunk k = c in [32k,32k+32); instr = [2c][128t], 512B/row ----
    const int lr = lane >> 5;           // 0/1: which of the 2 c-rows
    const int lt = (lane & 31) * 4;     // t offset (32 lanes x 16B = 512B row)
    #define STAGE(buf, k) do {                                                   \
        const int rb = (k) * KC + wid * 4;                                       \
        glds16(x1 + gB + (size_t)(rb + 0 + lr) * TLEN + t0 + lt, &xf[buf][(wid * 4 + 0) * TSPAN]); \
        glds16(x1 + gB + (size_t)(rb + 2 + lr) * TLEN + t0 + lt, &xf[buf][(wid * 4 + 2) * TSPAN]); \
        glds16(z  + gB + (size_t)(rb + 0 + lr) * TLEN + t0 + lt, &zf[buf][(wid * 4 + 0) * TSPAN]); \
        glds16(z  + gB + (size_t)(rb + 2 + lr) * TLEN + t0 + lt, &zf[buf][(wid * 4 + 2) * TSPAN]); \
    } while (0)

    // ---- repack: f32 staged -> masked/blended y bf16 [t][c-local] ----
    const int c_l = tid >> 4;            // 0..31
    const int t8  = (tid & 15) * 8;
    #define REPACK(buf) do {                                                     \
        const f32x4 xa = *reinterpret_cast<const f32x4*>(&xf[buf][c_l * TSPAN + t8]);     \
        const f32x4 xb = *reinterpret_cast<const f32x4*>(&xf[buf][c_l * TSPAN + t8 + 4]); \
        const f32x4 za = *reinterpret_cast<const f32x4*>(&zf[buf][c_l * TSPAN + t8]);     \
        const f32x4 zb = *reinterpret_cast<const f32x4*>(&zf[buf][c_l * TSPAN + t8 + 4]); \
        _Pragma("unroll")                                                        \
        for (int j = 0; j < 4; ++j) {                                            \
            const int ta = t8 + j, tb2 = t8 + 4 + j;                             \
            const float y0 = (t0 + ta  < pl) ? 0.0f : cz * za[j] + cx * xa[j];   \
            const float y1 = (t0 + tb2 < pl) ? 0.0f : cz * zb[j] + cx * xb[j];   \
            ybf[ta][ysw(ta, c_l)]   = f2bf(y0);                                  \
            ybf[tb2][ysw(tb2, c_l)] = f2bf(y1);                                  \
        }                                                                        \
    } while (0)

    // ---- extract: waves owning this chunk's d-slice keep z,x as packed bf16 ----
    unsigned pk[8][4];
    #define EXTRACT(buf, k) do {                                                 \
        if ((wid >> 1) == (k)) {                                                 \
            _Pragma("unroll")                                                    \
            for (int tt = 0; tt < 8; ++tt) {                                     \
                _Pragma("unroll")                                                \
                for (int rr = 0; rr < 4; ++rr) {                                 \
                    const int cl2 = (wid & 1) * 16 + q4 * 4 + rr;                \
                    const int tl  = tt * 16 + r15;                               \
                    const float zv = zf[buf][cl2 * TSPAN + tl];                  \
                    const float xv = xf[buf][cl2 * TSPAN + tl];                  \
                    pk[tt][rr] = ((unsigned)(unsigned short)f2bf(xv) << 16)      \
                               | (unsigned)(unsigned short)f2bf(zv);             \
                }                                                                \
            }                                                                    \
        }                                                                        \
    } while (0)

    // ---- MFMA: K-slice k accumulates into persistent acc[8] ----
    f32x4 acc[8];
    #pragma unroll
    for (int tt = 0; tt < 8; ++tt) acc[tt] = (f32x4){0.f, 0.f, 0.f, 0.f};
    #define MFMAK(k) do {                                                        \
        _Pragma("unroll")                                                        \
        for (int tt = 0; tt < 8; ++tt) {                                         \
            const int tr = tt * 16 + r15;                                        \
            const short8 ya = *reinterpret_cast<const short8*>(&ybf[tr][ysw(tr, q4 * 8)]); \
            acc[tt] = __builtin_amdgcn_mfma_f32_16x16x32_bf16(af[k], ya, acc[tt], 0, 0, 0); \
        }                                                                        \
    } while (0)

    // ================= pipelined K-chunk loop =================
    STAGE(0, 0); SB0;
    STAGE(1, 1); SB0;

    VMWAIT(4); SB0; bar_lgkm();          // S0 landed (af retired), S1 in flight
    REPACK(0); EXTRACT(0, 0); bar_lgkm();
    MFMAK(0); STAGE(0, 2); SB0;

    VMWAIT(4); SB0; bar_lgkm();          // S1 landed, S2 in flight
    REPACK(1); EXTRACT(1, 1); bar_lgkm();
    MFMAK(1); STAGE(1, 3); SB0;

    VMWAIT(4); SB0; bar_lgkm();          // S2 landed, S3 in flight
    REPACK(0); EXTRACT(0, 2); bar_lgkm();
    MFMAK(2);

    VMWAIT(0); SB0; bar_lgkm();          // S3 landed
    REPACK(1); EXTRACT(1, 3); bar_lgkm();
    MFMAK(3);

    // ---- epilogue: monolithic store burst + loss ----
    float lsum = 0.0f;
    #pragma unroll
    for (int rr = 0; rr < 4; ++rr) {
        const int d = wid * 16 + q4 * 4 + rr;
        float* orow = out + 1 + (size_t)(b * CC + d) * TLEN + t0;
        #pragma unroll
        for (int tt = 0; tt < 8; ++tt) {
            const int tl = tt * 16 + r15;
            const int tg = t0 + tl;
            const unsigned p = pk[tt][rr];
            const float zv = bf2f((unsigned short)(p & 0xFFFFu));
            const float xv = bf2f((unsigned short)(p >> 16));
            const float ov = acc[tt][rr] + bl[rr];
            const float o2 = ov + oms * zv;
            orow[tl] = o2;
            if ((tg >= pl) & (tg < xl)) {
                const float df = o2 - xv;
                lsum += df * df;
            }
        }
    }

    // ---- loss: wave reduce -> block reduce -> one atomicAdd ----
    #pragma unroll
    for (int off = 32; off >= 1; off >>= 1) lsum += __shfl_down(lsum, off);
    if (lane == 0) red[wid] = lsum;
    __syncthreads();
    if (tid == 0) {
        float s = 0.0f;
        #pragma unroll
        for (int w = 0; w < 8; ++w) s += red[w];
        atomicAdd(out, s / (1024.0f * (float)(xl - pl)));   // 1/(B*C*(xl-pl))
    }
}

extern "C" void kernel_launch(void* const* d_in, const int* in_sizes, int n_in,
                              void* d_out, int out_size, void* d_ws, size_t ws_size,
                              hipStream_t stream) {
    const float* x1    = (const float*)d_in[0];
    // d_in[1] = mu (unused), d_in[2] = style (unused)
    const float* tsm   = (const float*)d_in[3];
    const float* z     = (const float*)d_in[4];
    const float* W     = (const float*)d_in[5];
    const float* blin  = (const float*)d_in[6];
    const int*   xlens = (const int*)d_in[7];
    const int*   plens = (const int*)d_in[8];
    float* out = (float*)d_out;

    hipMemsetAsync(out, 0, sizeof(float), stream);   // zero the loss slot
    cfm_fused<<<NB, 512, 0, stream>>>(x1, tsm, z, W, blin, xlens, plens, out);
}

// Round 15
// 30.857 us; speedup vs baseline: 1.1576x; 1.1576x over previous
//
#include <hip/hip_runtime.h>
#include <hip/hip_bf16.h>

#define BB    8
#define CC    128
#define TLEN  8192
#define TT    32                      // t per tile
#define TSPAN 128                     // 4 tiles per block
#define NB    (BB * (TLEN / TSPAN))   // 512 blocks = 2/CU

typedef __attribute__((ext_vector_type(8))) short short8;
typedef __attribute__((ext_vector_type(4))) float f32x4;

__device__ __forceinline__ short f2bf(float f) {
    union { float f; unsigned u; } v; v.f = f;
    return (short)((v.u + 0x7FFFu + ((v.u >> 16) & 1u)) >> 16);
}
__device__ __forceinline__ float bf2f(unsigned short h) {
    union { unsigned u; float f; } v; v.u = ((unsigned)h) << 16;
    return v.f;
}
// y-tile swizzle (c-octets XOR by t-hash) — verified R5..R13
__device__ __forceinline__ int swzY(int t, int c) {
    return c ^ (((t ^ (t >> 3)) & 15) << 3);
}
// f32/u32 staging swizzle on the 32-elem t-row, keyed by c — verified R13
__device__ __forceinline__ int sfz(int c) {
    return ((c & 3) << 3) | (((c >> 2) & 1) << 2);
}

#define VMWAIT(N) asm volatile("s_waitcnt vmcnt(" #N ")" ::: "memory")
#define SB0 __builtin_amdgcn_sched_barrier(0)

__device__ __forceinline__ void bar_lgkm() {
    asm volatile("s_waitcnt lgkmcnt(0)" ::: "memory");
    __builtin_amdgcn_s_barrier();
}

typedef __attribute__((address_space(1))) const unsigned GU;
typedef __attribute__((address_space(3))) unsigned LU;
__device__ __forceinline__ void glds16(const float* g, const float* l) {
    __builtin_amdgcn_global_load_lds((GU*)g, (LU*)l, 16, 0, 0);
}
// asm-pinned vector load: result registers must stay allocated & in flight
__device__ __forceinline__ f32x4 gload(const float* base, unsigned byteoff) {
    f32x4 r;
    asm volatile("global_load_dwordx4 %0, %1, %2"
                 : "=v"(r) : "v"(byteoff), "s"(base));
    return r;
}

__global__ __launch_bounds__(512, 4)
void cfm_fused(const float* __restrict__ x1, const float* __restrict__ tsm,
               const float* __restrict__ z, const float* __restrict__ W,
               const float* __restrict__ blin, const int* __restrict__ xlens,
               const int* __restrict__ plens, float* __restrict__ out)
{
    __shared__ float    zfb[2][CC * TT];  // z f32 [c][32t] sfz-swizzled, dbuf 32KB
    __shared__ short    ybf[TT][CC];      // y bf16 [t][c] swzY, 8KB
    __shared__ unsigned zxpk[CC * TT];    // (x<<16|z) bf16 [d][32t] sfz, 16KB
    __shared__ float    red[8];

    const int bi = blockIdx.x;
    const int b  = bi & 7;
    const int tb = (bi >> 3) * TSPAN;

    const int tid  = threadIdx.x;
    const int lane = tid & 63;
    const int wid  = tid >> 6;
    const int r15  = lane & 15;
    const int q4   = lane >> 4;

    const float ts  = tsm[b];
    const int   pl  = plens[b];
    const int   xl  = xlens[b];
    const float oms = 0.999999f;          // 1 - sigma
    const float cz  = 1.0f - oms * ts;
    const float cx  = ts;
    const size_t gB = (size_t)b * CC * TLEN;

    // ---- W A-frags (cvt forces the waits -> retired before first VMWAIT) ----
    short8 af[4];
    {
        const int row = wid * 16 + r15;
        #pragma unroll
        for (int ks = 0; ks < 4; ++ks) {
            const float4 w0 = *reinterpret_cast<const float4*>(W + row * CC + ks * 32 + q4 * 8);
            const float4 w1 = *reinterpret_cast<const float4*>(W + row * CC + ks * 32 + q4 * 8 + 4);
            short8 a;
            a[0] = f2bf(w0.x); a[1] = f2bf(w0.y); a[2] = f2bf(w0.z); a[3] = f2bf(w0.w);
            a[4] = f2bf(w1.x); a[5] = f2bf(w1.y); a[6] = f2bf(w1.z); a[7] = f2bf(w1.w);
            af[ks] = a;
        }
    }
    // bias: float4 + asm pin so the load retires now (keeps vmcnt counts exact)
    f32x4 blv = *reinterpret_cast<const f32x4*>(blin + wid * 16 + q4 * 4);
    asm volatile("" :: "v"(blv));

    // ---- staging geometry ----
    const int cl  = lane >> 3;                       // 0..7 within chunk
    const int tsw = ((lane & 7) * 4) ^ sfz(cl);      // inverse-swz source t
    const int ca  = wid * 16, cb = ca + 8;
    #define STAGEZ(buf, t0k) do {                                             \
        glds16(z + gB + (size_t)(ca + cl) * TLEN + (t0k) + tsw, &zfb[buf][ca * TT]); \
        glds16(z + gB + (size_t)(cb + cl) * TLEN + (t0k) + tsw, &zfb[buf][cb * TT]); \
    } while (0)

    const int rc  = tid >> 2;                        // c (and later d) row
    const int t8  = (tid & 3) * 8;
    const int fz  = sfz(rc);
    const unsigned xoff = (unsigned)((gB + (size_t)rc * TLEN) * 4);
    #define XLOAD(xr, t0k) do {                                               \
        xr[0] = gload(x1, xoff + ((t0k) + t8) * 4u);                          \
        xr[1] = gload(x1, xoff + ((t0k) + t8 + 4) * 4u);                      \
    } while (0)

    // ---- repack: z LDS + x regs -> y bf16 tile + packed zx tile ----
    #define REPACK(buf, t0k, xr) do {                                         \
        const int idx = (rc * TT + t8) ^ fz;                                  \
        const f32x4 za = *reinterpret_cast<const f32x4*>(&zfb[buf][idx]);     \
        const f32x4 zb = *reinterpret_cast<const f32x4*>(&zfb[buf][idx ^ 4]); \
        _Pragma("unroll")                                                     \
        for (int j = 0; j < 4; ++j) {                                         \
            const int ta = t8 + j, tb2 = t8 + 4 + j;                          \
            const float y0 = ((t0k) + ta  < pl) ? 0.0f : cz * za[j] + cx * xr[0][j]; \
            const float y1 = ((t0k) + tb2 < pl) ? 0.0f : cz * zb[j] + cx * xr[1][j]; \
            ybf[ta][swzY(ta, rc)]   = f2bf(y0);                               \
            ybf[tb2][swzY(tb2, rc)] = f2bf(y1);                               \
            zxpk[idx + j]       = ((unsigned)(unsigned short)f2bf(xr[0][j]) << 16) \
                                | (unsigned)(unsigned short)f2bf(za[j]);      \
            zxpk[(idx ^ 4) + j] = ((unsigned)(unsigned short)f2bf(xr[1][j]) << 16) \
                                | (unsigned)(unsigned short)f2bf(zb[j]);      \
        }                                                                     \
    } while (0)

    // ---- MFMA + epilogue (reads ybf + zxpk only; 8 stores/thread) ----
    float lsum = 0.0f;
    #define COMPUTE(t0k) do {                                                 \
        f32x4 acc[2];                                                         \
        acc[0] = (f32x4){0,0,0,0}; acc[1] = (f32x4){0,0,0,0};                 \
        _Pragma("unroll")                                                     \
        for (int ks = 0; ks < 4; ++ks) {                                      \
            _Pragma("unroll")                                                 \
            for (int tt = 0; tt < 2; ++tt) {                                  \
                const int tr = tt * 16 + r15;                                 \
                const short8 ya = *reinterpret_cast<const short8*>(           \
                    &ybf[tr][swzY(tr, ks * 32 + q4 * 8)]);                    \
                acc[tt] = __builtin_amdgcn_mfma_f32_16x16x32_bf16(af[ks], ya, acc[tt], 0, 0, 0); \
            }                                                                 \
        }                                                                     \
        _Pragma("unroll")                                                     \
        for (int rr = 0; rr < 4; ++rr) {                                      \
            const int d = wid * 16 + q4 * 4 + rr;                             \
            float* orow = out + 1 + (size_t)(b * CC + d) * TLEN + (t0k);      \
            const int fd = sfz(d);                                            \
            _Pragma("unroll")                                                 \
            for (int tt = 0; tt < 2; ++tt) {                                  \
                const int tl = tt * 16 + r15;                                 \
                const unsigned p = zxpk[(d * TT + tl) ^ fd];                  \
                const float zv = bf2f((unsigned short)(p & 0xFFFFu));         \
                const float xv = bf2f((unsigned short)(p >> 16));             \
                const float o2 = acc[tt][rr] + blv[rr] + oms * zv;            \
                orow[tl] = o2;                                                \
                const int tg = (t0k) + tl;                                    \
                if ((tg >= pl) & (tg < xl)) { const float df = o2 - xv; lsum += df * df; } \
            }                                                                 \
        }                                                                     \
    } while (0)

    // ================= 4-tile pipeline =================
    f32x4 x0r[2], x1r[2];
    STAGEZ(0, tb);          XLOAD(x0r, tb);          SB0;   // 4 outstanding
    STAGEZ(1, tb + TT);     XLOAD(x1r, tb + TT);     SB0;   // 8

    // tile 0
    VMWAIT(4); SB0; bar_lgkm();
    REPACK(0, tb, x0r);
    bar_lgkm();
    STAGEZ(0, tb + 2 * TT); XLOAD(x0r, tb + 2 * TT); SB0;
    COMPUTE(tb);

    // tile 1
    VMWAIT(12); SB0; bar_lgkm();
    REPACK(1, tb + TT, x1r);
    bar_lgkm();
    STAGEZ(1, tb + 3 * TT); XLOAD(x1r, tb + 3 * TT); SB0;
    COMPUTE(tb + TT);

    // tile 2
    VMWAIT(20); SB0; bar_lgkm();
    REPACK(0, tb + 2 * TT, x0r);
    bar_lgkm();
    COMPUTE(tb + 2 * TT);

    // tile 3
    VMWAIT(16); SB0; bar_lgkm();
    REPACK(1, tb + 3 * TT, x1r);
    bar_lgkm();
    COMPUTE(tb + 3 * TT);

    // ---- loss: wave reduce -> block reduce -> one atomicAdd ----
    #pragma unroll
    for (int off = 32; off >= 1; off >>= 1) lsum += __shfl_down(lsum, off);
    if (lane == 0) red[wid] = lsum;
    __syncthreads();
    if (tid == 0) {
        float s = 0.0f;
        #pragma unroll
        for (int w = 0; w < 8; ++w) s += red[w];
        atomicAdd(out, s / (1024.0f * (float)(xl - pl)));   // 1/(B*C*(xl-pl))
    }
}

extern "C" void kernel_launch(void* const* d_in, const int* in_sizes, int n_in,
                              void* d_out, int out_size, void* d_ws, size_t ws_size,
                              hipStream_t stream) {
    const float* x1    = (const float*)d_in[0];
    // d_in[1] = mu (unused), d_in[2] = style (unused)
    const float* tsm   = (const float*)d_in[3];
    const float* z     = (const float*)d_in[4];
    const float* W     = (const float*)d_in[5];
    const float* blin  = (const float*)d_in[6];
    const int*   xlens = (const int*)d_in[7];
    const int*   plens = (const int*)d_in[8];
    float* out = (float*)d_out;

    hipMemsetAsync(out, 0, sizeof(float), stream);   // zero the loss slot
    cfm_fused<<<NB, 512, 0, stream>>>(x1, tsm, z, W, blin, xlens, plens, out);
}